// Round 6
// baseline (2498.587 us; speedup 1.0000x reference)
//
#include <hip/hip_runtime.h>
#include <hip/hip_bf16.h>

// QuantizedLinearINT4: out = x @ dequant(W).T + bias
// M=8192, N=OUT=4096, K=IN=4096.
// Round-6: staging-bandwidth attack. 512x256 tile (staged bytes/FLOP x0.75),
// BK=32, 1024 threads = 16 waves (4Mx4N), grid 256 = 1 block/CU single pass,
// triple-buffered LDS (144 KiB) with 2-phase staging lead and counted vmcnt(3).
// Phase body reverted to round-4 form: 12 ds_read -> stage 3 -> 32 MFMA.

typedef __bf16 bf16;
typedef __attribute__((ext_vector_type(8))) __bf16 bf16x8;
typedef __attribute__((ext_vector_type(4))) float f32x4;
typedef __attribute__((ext_vector_type(4))) unsigned int u32x4;

#define OUT_DIM 4096
#define IN_DIM  4096
#define M_DIM   8192

// ---------- Pass 1: dequant int4 -> bf16 W[OUT][IN] ----------
__global__ __launch_bounds__(256) void dequant_w_kernel(
    const int* __restrict__ wp, const float* __restrict__ scale,
    const float* __restrict__ zp, bf16* __restrict__ W)
{
  const int t = blockIdx.x * 256 + threadIdx.x;
  const long j = (long)t * 8;
  const int o = (int)(j >> 12);
  const float s = scale[o];
  const float zs = zp[o] * s;
  const int4 p = *(const int4*)(wp + (long)t * 4);
  const int v[4] = {p.x, p.y, p.z, p.w};
  union { bf16 h[8]; u32x4 u; } r;
#pragma unroll
  for (int q = 0; q < 4; ++q) {
    r.h[2*q]   = (bf16)((float)(v[q] & 15) * s - zs);
    r.h[2*q+1] = (bf16)((float)((v[q] >> 4) & 15) * s - zs);
  }
  *(u32x4*)(W + j) = r.u;
}

// ---------- Pass 2: cast x f32 -> bf16 ----------
__global__ __launch_bounds__(256) void cvt_x_kernel(
    const float* __restrict__ x, bf16* __restrict__ xb)
{
  const long t = (long)blockIdx.x * 256 + threadIdx.x;
  const long i = t * 8;
  const f32x4 a = *(const f32x4*)(x + i);
  const f32x4 b = *(const f32x4*)(x + i + 4);
  union { bf16 h[8]; u32x4 u; } r;
#pragma unroll
  for (int q = 0; q < 4; ++q) { r.h[q] = (bf16)a[q]; r.h[4+q] = (bf16)b[q]; }
  *(u32x4*)(xb + i) = r.u;
}

// ---------- Pass 3: 512x256 tile, BK=32, 16-wave GEMM-BT with fused bias ----------
// C[M][N] = A[M][K] * B[N][K]^T + bias.  1024 threads = 16 waves (4M x 4N),
// per-wave output 128x64 = acc[8][4].  LDS: smA[3][512][32] + smB[3][256][32]
// bf16 (144 KiB), st_16x32 swizzle (byte ^= ((byte>>9)&1)<<5), linear
// gload_lds dest + pre-swizzled global source + swizzled ds_read.
// Phase T (one per 32-K tile): vmcnt(3) -> barrier -> 12 ds_read_b128 ->
// stage tile T+2 (3 gload_lds calls) -> 32 MFMA (compiler-counted lgkm).
__global__ __launch_bounds__(1024, 4) void gemm_bt_bias_kernel(
    const bf16* __restrict__ A, const bf16* __restrict__ B,
    const float* __restrict__ bias, float* __restrict__ C)
{
  const int N = OUT_DIM, K = IN_DIM;
  const int NT = IN_DIM / 32;            // 128 K-tiles (one phase each)

  __shared__ bf16 smA[3][512][32];       // 96 KiB
  __shared__ bf16 smB[3][256][32];       // 48 KiB

  // T1: XCD-aware bijective swizzle (256 blocks, 256 % 8 == 0)
  const int bid = blockIdx.x;
  const int swz = (bid & 7) * (256 / 8) + (bid >> 3);
  const int bm = swz >> 4;               // 16 row-tiles (512 rows each)
  const int bn = swz & 15;               // 16 col-tiles (256 cols each)

  const int tid  = threadIdx.x;
  const int wave = tid >> 6;
  const int lane = tid & 63;
  const int wr = wave >> 2;              // 0..3 -> 128-row strip
  const int wc = wave & 3;               // 0..3 -> 64-col strip

  const long row0 = (long)bm * 512;
  const long col0 = (long)bn * 256;

  // --- staging source addresses (pre-swizzled: linear LDS dest, swizzled global src) ---
  // Each thread covers byte L = tid*16 of a 16 KiB chunk; A half = 2 chunks, B half = 1.
  const int L  = tid * 16;
  const int Lw = L ^ (((L >> 9) & 1) << 5);
  const int sr = Lw >> 6;                // row 0..255 within chunk
  const int sc = (Lw & 63) >> 1;         // bf16 col 0..31
  const bf16* aA0 = A + (row0 + sr)       * (long)K + sc;
  const bf16* aA1 = A + (row0 + sr + 256) * (long)K + sc;
  const bf16* aB0 = B + (col0 + sr)       * (long)K + sc;

  // Stage one 32-K tile into buffer BUF at K-offset KOFF (3 wave-level ops/thread)
#define STAGE_TILE(BUF, KOFF) do {                                              \
    char* Ah = (char*)&smA[BUF][0][0];                                          \
    char* Bh = (char*)&smB[BUF][0][0];                                          \
    __builtin_amdgcn_global_load_lds(                                           \
        (const __attribute__((address_space(1))) void*)(aA0 + (KOFF)),          \
        (__attribute__((address_space(3))) void*)(Ah + L), 16, 0, 0);           \
    __builtin_amdgcn_global_load_lds(                                           \
        (const __attribute__((address_space(1))) void*)(aA1 + (KOFF)),          \
        (__attribute__((address_space(3))) void*)(Ah + 16384 + L), 16, 0, 0);   \
    __builtin_amdgcn_global_load_lds(                                           \
        (const __attribute__((address_space(1))) void*)(aB0 + (KOFF)),          \
        (__attribute__((address_space(3))) void*)(Bh + L), 16, 0, 0);           \
  } while (0)

  // --- ds_read per-lane constants (swizzle folds to ^((lane&8)<<2)) ---
  const int lane15 = lane & 15;
  const int rb = (lane15 * 64 + ((lane >> 4) << 4)) ^ ((lane & 8) << 2);
  const int wrB = wr * 8192;             // byte offset of wave's 128-row strip in A half
  const int wcB = wc * 4096;             // byte offset of wave's 64-row strip in B half

  f32x4 acc[8][4] = {};

  // Prologue: stage tiles 0 and 1 -> bufs 0,1 (6 ops in flight)
  STAGE_TILE(0, 0);
  STAGE_TILE(1, 32);

  int buf = 0;
  for (int T = 0; T < NT; ++T) {
    if (T == NT - 1) asm volatile("s_waitcnt vmcnt(0)" ::: "memory");
    else             asm volatile("s_waitcnt vmcnt(3)" ::: "memory");
    __builtin_amdgcn_s_barrier();
    asm volatile("" ::: "memory");       // keep ds_reads below the barrier

    const char* Ab = (const char*)&smA[buf][0][0];
    const char* Bb = (const char*)&smB[buf][0][0];
    bf16x8 fb[4], fa[8];
#pragma unroll
    for (int f = 0; f < 4; ++f) fb[f] = *(const bf16x8*)(Bb + wcB + f * 1024 + rb);
#pragma unroll
    for (int f = 0; f < 8; ++f) fa[f] = *(const bf16x8*)(Ab + wrB + f * 1024 + rb);

    if (T + 2 < NT) {
      int bufn = buf + 2; if (bufn >= 3) bufn -= 3;
      STAGE_TILE(bufn, (T + 2) * 32);
    }

    __builtin_amdgcn_s_setprio(1);
#pragma unroll
    for (int i = 0; i < 8; ++i)
#pragma unroll
      for (int j = 0; j < 4; ++j)
        acc[i][j] = __builtin_amdgcn_mfma_f32_16x16x32_bf16(fa[i], fb[j], acc[i][j], 0, 0, 0);
    __builtin_amdgcn_s_setprio(0);

    ++buf; if (buf >= 3) buf = 0;
  }

  // Epilogue: C/D layout col=lane&15, row=(lane>>4)*4+reg; fused bias.
  const long cr0 = row0 + wr * 128 + ((lane >> 4) << 2);
  const long cc0 = col0 + wc * 64 + lane15;
#pragma unroll
  for (int j = 0; j < 4; ++j) {
    const long gc = cc0 + j * 16;
    const float bv = bias[gc];
#pragma unroll
    for (int mf = 0; mf < 8; ++mf) {
      float* cp = C + (cr0 + mf * 16) * (long)N + gc;
#pragma unroll
      for (int r = 0; r < 4; ++r)
        cp[(long)r * N] = acc[mf][j][r] + bv;
    }
  }
#undef STAGE_TILE
}

extern "C" void kernel_launch(void* const* d_in, const int* in_sizes, int n_in,
                              void* d_out, int out_size, void* d_ws, size_t ws_size,
                              hipStream_t stream)
{
  const float* x     = (const float*)d_in[0];
  const int*   wp    = (const int*)d_in[1];
  const float* scale = (const float*)d_in[2];
  const float* zp    = (const float*)d_in[3];
  const float* bias  = (const float*)d_in[4];
  float* out = (float*)d_out;

  bf16* Wb = (bf16*)d_ws;
  bf16* Xb = (bf16*)((char*)d_ws + (size_t)OUT_DIM * IN_DIM * 2);

  dequant_w_kernel<<<(OUT_DIM * (long)IN_DIM / 8) / 256, 256, 0, stream>>>(wp, scale, zp, Wb);
  cvt_x_kernel<<<(M_DIM * (long)IN_DIM / 8) / 256, 256, 0, stream>>>(x, Xb);
  // grid = (8192/512)*(4096/256) = 16*16 = 256 blocks, 1024 threads
  gemm_bt_bias_kernel<<<256, 1024, 0, stream>>>(Xb, Wb, bias, out);
}

// Round 8
// 335.143 us; speedup vs baseline: 7.4553x; 7.4553x over previous
//
#include <hip/hip_runtime.h>
#include <hip/hip_bf16.h>

// QuantizedLinearINT4: out = x @ dequant(W).T + bias
// M=8192, N=OUT=4096, K=IN=4096.
// Round-8: fused-dequant GEMM, fixed input container. weight_packed is an
// INT32 array (one packed byte per element) -> repack pass to a true byte
// array first (8.4 MB), then the GEMM stages packed nibbles into LDS
// (4 KB/K-half vs 16 KB bf16) and dequantizes B fragments in-register.
// GEMM schedule = round-4 proven: 256x256, BK=64, 512 thr (8 waves 2Mx4N),
// 2 phases/K-tile, vmcnt(4) counted staging, st_16x32 A swizzle, XCD swizzle.

typedef __bf16 bf16;
typedef __attribute__((ext_vector_type(8))) __bf16 bf16x8;
typedef __attribute__((ext_vector_type(4))) float f32x4;
typedef __attribute__((ext_vector_type(4))) unsigned int u32x4;

#define OUT_DIM 4096
#define IN_DIM  4096
#define M_DIM   8192

// ---------- Pass 1: cast x f32 -> bf16 ----------
__global__ __launch_bounds__(256) void cvt_x_kernel(
    const float* __restrict__ x, bf16* __restrict__ xb)
{
  const long t = (long)blockIdx.x * 256 + threadIdx.x;
  const long i = t * 8;
  const f32x4 a = *(const f32x4*)(x + i);
  const f32x4 b = *(const f32x4*)(x + i + 4);
  union { bf16 h[8]; u32x4 u; } r;
#pragma unroll
  for (int q = 0; q < 4; ++q) { r.h[q] = (bf16)a[q]; r.h[4+q] = (bf16)b[q]; }
  *(u32x4*)(xb + i) = r.u;
}

// ---------- Pass 2: repack int32 -> bytes ----------
// wp[e] in [0,256): one byte per int32. Emit dense byte array (16 entries/thread).
__global__ __launch_bounds__(256) void repack_w_kernel(
    const int* __restrict__ wp, unsigned int* __restrict__ wb)
{
  const long t = (long)blockIdx.x * 256 + threadIdx.x;   // 524,288 threads
  const long e = t * 16;
  u32x4 r;
#pragma unroll
  for (int q = 0; q < 4; ++q) {
    const int4 p = *(const int4*)(wp + e + q * 4);
    r[q] = (unsigned)(p.x & 255) | ((unsigned)(p.y & 255) << 8) |
           ((unsigned)(p.z & 255) << 16) | ((unsigned)(p.w & 255) << 24);
  }
  *(u32x4*)(wb + t * 4) = r;
}

// ---------- Pass 3: 256x256 fused-dequant GEMM with bias ----------
// C[M][N] = A[M][K] * W^T + bias, W[n][k] = nib(n,k)*scale[n] - zp[n]*scale[n].
// LDS: smA[2 buf][2 ks][256][32] bf16 (64 KB, st_16x32 swizzled),
//      smB[2 buf][2 ks][256][4] u32 (16 KB, packed nibbles, row = out-col).
// Phase (2 per K-tile): vmcnt(4) -> barrier -> 4 b32 B-reads + 8 b128 A-reads
// -> stage next (2x16B A + 2x4B B) -> dequant B frags -> 32 MFMA.
__global__ __launch_bounds__(512, 2) void gemm_bt_bias_kernel(
    const bf16* __restrict__ A, const unsigned char* __restrict__ WP,
    const float* __restrict__ scale, const float* __restrict__ zp,
    const float* __restrict__ bias, float* __restrict__ C)
{
  const int N = OUT_DIM, K = IN_DIM;
  const int NT = IN_DIM / 64;            // 64 K-tiles

  __shared__ bf16 smA[2][2][256][32];          // 64 KiB
  __shared__ unsigned int smB[2][2][256][4];   // 16 KiB

  // T1: XCD-aware bijective swizzle (512 blocks, 512 % 8 == 0)
  const int bid = blockIdx.x;
  const int swz = (bid & 7) * (512 / 8) + (bid >> 3);
  const int bm = swz >> 4;               // 32 row-tiles
  const int bn = swz & 15;               // 16 col-tiles

  const int tid  = threadIdx.x;
  const int wave = tid >> 6;
  const int lane = tid & 63;
  const int wr = wave >> 2;              // 0..1 -> 128-row strip
  const int wc = wave & 3;               // 0..3 -> 64-col strip

  const long row0 = (long)bm * 256;
  const long col0 = (long)bn * 256;

  // --- A staging source (pre-swizzled: linear LDS dest, swizzled global src) ---
  const int L0 = tid * 16;
  const int L1 = 8192 + tid * 16;
  const int Lw0 = L0 ^ (((L0 >> 9) & 1) << 5);
  const int Lw1 = L1 ^ (((L1 >> 9) & 1) << 5);
  const int sr0 = Lw0 >> 6, sc0 = (Lw0 & 63) >> 1;
  const int sr1 = Lw1 >> 6, sc1 = (Lw1 & 63) >> 1;
  const bf16* a0 = A + (row0 + sr0) * (long)K + sc0;
  const bf16* a1 = A + (row0 + sr1) * (long)K + sc1;

  // --- B staging source: packed row (col0+r) is 2048 bytes ---
  const int brow  = tid >> 2;
  const int bbyte = (tid & 3) * 4;
  const unsigned char* w0 = WP + (col0 + brow) * 2048L + bbyte;
  const unsigned char* w1 = WP + (col0 + brow + 128) * 2048L + bbyte;

  // Stage one (tile,ks) group: A half (2x16B) then B half (2x4B) = 4 ops/wave.
#define STAGE_G(BUF, KS, KOFF) do {                                             \
    char* Ah = (char*)&smA[BUF][KS][0][0];                                      \
    char* Bh = (char*)&smB[BUF][KS][0][0];                                      \
    __builtin_amdgcn_global_load_lds(                                           \
        (const __attribute__((address_space(1))) void*)(a0 + (KOFF)),           \
        (__attribute__((address_space(3))) void*)(Ah + L0), 16, 0, 0);          \
    __builtin_amdgcn_global_load_lds(                                           \
        (const __attribute__((address_space(1))) void*)(a1 + (KOFF)),           \
        (__attribute__((address_space(3))) void*)(Ah + L1), 16, 0, 0);          \
    __builtin_amdgcn_global_load_lds(                                           \
        (const __attribute__((address_space(1))) void*)(w0 + ((KOFF) >> 1)),    \
        (__attribute__((address_space(3))) void*)(Bh + tid * 4), 4, 0, 0);      \
    __builtin_amdgcn_global_load_lds(                                           \
        (const __attribute__((address_space(1))) void*)(w1 + ((KOFF) >> 1)),    \
        (__attribute__((address_space(3))) void*)(Bh + 2048 + tid * 4), 4, 0, 0);\
  } while (0)

  // --- read-side per-lane constants ---
  const int lane15 = lane & 15;
  const int rb  = (lane15 * 64 + ((lane >> 4) << 4)) ^ ((lane & 8) << 2);  // A (swizzled)
  const int wrB = wr * 8192;             // A: wave's 128-row strip byte offset
  const int rBb = (wc * 64 + lane15) * 16 + ((lane >> 4) << 2);            // B packed b32

  // per-lane dequant constants for the 4 B-frag columns
  float sv[4], zv[4];
#pragma unroll
  for (int f = 0; f < 4; ++f) {
    const int n = (int)col0 + wc * 64 + f * 16 + lane15;
    sv[f] = scale[n];
    zv[f] = zp[n] * sv[f];
  }

  f32x4 acc[8][4] = {};

#define PHASE(BUF, KS, STAGE_STMT, VM_STMT) do {                                \
    VM_STMT;                                                                    \
    __builtin_amdgcn_s_barrier();                                               \
    asm volatile("" ::: "memory");  /* keep LDS reads below the barrier */      \
    const char* Ab = (const char*)&smA[BUF][KS][0][0];                          \
    const char* Bp = (const char*)&smB[BUF][KS][0][0];                          \
    unsigned int pk[4];                                                         \
    _Pragma("unroll")                                                           \
    for (int f = 0; f < 4; ++f) pk[f] = *(const unsigned int*)(Bp + rBb + f * 256); \
    bf16x8 fa[8];                                                               \
    _Pragma("unroll")                                                           \
    for (int f = 0; f < 8; ++f) fa[f] = *(const bf16x8*)(Ab + wrB + f * 1024 + rb); \
    STAGE_STMT;                                                                 \
    bf16x8 fb[4];                                                               \
    _Pragma("unroll")                                                           \
    for (int f = 0; f < 4; ++f) {                                               \
      const float fs = sv[f], fz = zv[f];                                       \
      _Pragma("unroll")                                                         \
      for (int e = 0; e < 8; ++e)                                               \
        fb[f][e] = (bf16)((float)((pk[f] >> (4 * e)) & 15u) * fs - fz);         \
    }                                                                           \
    __builtin_amdgcn_s_setprio(1);                                              \
    _Pragma("unroll")                                                           \
    for (int i = 0; i < 8; ++i)                                                 \
      _Pragma("unroll")                                                         \
      for (int j = 0; j < 4; ++j)                                               \
        acc[i][j] = __builtin_amdgcn_mfma_f32_16x16x32_bf16(fa[i], fb[j], acc[i][j], 0, 0, 0); \
    __builtin_amdgcn_s_setprio(0);                                              \
  } while (0)

  // Prologue: tile 0, both ks groups (8 ops in flight)
  STAGE_G(0, 0, 0);
  STAGE_G(0, 1, 32);

  for (int T = 0; T < NT; ++T) {
    const int buf = T & 1;
    const int nbuf = buf ^ 1;
    const int nko = (T + 1) * 64;
    const bool st = (T + 1 < NT);

    // phase A (ks=0): consume (T,0); stage (T+1,0)
    PHASE(buf, 0,
          { if (st) STAGE_G(nbuf, 0, nko); },
          { asm volatile("s_waitcnt vmcnt(4)" ::: "memory"); });
    // phase B (ks=1): consume (T,1); stage (T+1,1)
    PHASE(buf, 1,
          { if (st) STAGE_G(nbuf, 1, nko + 32); },
          { if (T == NT - 1) asm volatile("s_waitcnt vmcnt(0)" ::: "memory");
            else             asm volatile("s_waitcnt vmcnt(4)" ::: "memory"); });
  }

  // Epilogue: C/D layout col=lane&15, row=(lane>>4)*4+reg; fused bias.
  const long cr0 = row0 + wr * 128 + ((lane >> 4) << 2);
  const long cc0 = col0 + wc * 64 + lane15;
#pragma unroll
  for (int j = 0; j < 4; ++j) {
    const long gc = cc0 + j * 16;
    const float bv = bias[gc];
#pragma unroll
    for (int mf = 0; mf < 8; ++mf) {
      float* cp = C + (cr0 + mf * 16) * (long)N + gc;
#pragma unroll
      for (int r = 0; r < 4; ++r)
        cp[(long)r * N] = acc[mf][j][r] + bv;
    }
  }
#undef PHASE
#undef STAGE_G
}

extern "C" void kernel_launch(void* const* d_in, const int* in_sizes, int n_in,
                              void* d_out, int out_size, void* d_ws, size_t ws_size,
                              hipStream_t stream)
{
  const float* x     = (const float*)d_in[0];
  const int*   wp    = (const int*)d_in[1];     // int32 per packed byte!
  const float* scale = (const float*)d_in[2];
  const float* zp    = (const float*)d_in[3];
  const float* bias  = (const float*)d_in[4];
  float* out = (float*)d_out;

  bf16* Xb = (bf16*)d_ws;                                         // 67,108,864 B
  unsigned int* Wb = (unsigned int*)((char*)d_ws + 67108864);     //  8,388,608 B

  cvt_x_kernel<<<(M_DIM * (long)IN_DIM / 8) / 256, 256, 0, stream>>>(x, Xb);
  repack_w_kernel<<<(OUT_DIM * (long)IN_DIM / 2 / 16) / 256, 256, 0, stream>>>(wp, Wb);
  // grid = (8192/256)*(4096/256) = 32*16 = 512 blocks, 512 threads
  gemm_bt_bias_kernel<<<512, 512, 0, stream>>>(
      Xb, (const unsigned char*)Wb, scale, zp, bias, out);
}

// Round 9
// 310.699 us; speedup vs baseline: 8.0418x; 1.0787x over previous
//
#include <hip/hip_runtime.h>
#include <hip/hip_bf16.h>

// QuantizedLinearINT4: out = x @ dequant(W).T + bias
// M=8192, N=OUT=4096, K=IN=4096.
// Round-9: scale-factored fused dequant. B staged as packed nibbles; B frag
// built as bf16(1 + nib/16) via pure bit ops (0x3F80 | nib<<3); scale/zp
// applied in epilogue: out = 16*s*acc - s*(16+zp)*rowsum + bias, rowsum
// computed in the cvt_x pass. smB laid out so each lane's 4 frag-words are
// one contiguous ds_read_b128. Schedule = round-4 proven (256x256, BK=64,
// 512 thr, 2 phases/K-tile, vmcnt(4), st_16x32 A swizzle, XCD swizzle).

typedef __bf16 bf16;
typedef __attribute__((ext_vector_type(8))) __bf16 bf16x8;
typedef __attribute__((ext_vector_type(4))) float f32x4;
typedef __attribute__((ext_vector_type(4))) unsigned int u32x4;

#define OUT_DIM 4096
#define IN_DIM  4096
#define M_DIM   8192

// ---------- Pass 1: cast x f32 -> bf16, accumulate per-row sums ----------
__global__ __launch_bounds__(256) void cvt_x_kernel(
    const float* __restrict__ x, bf16* __restrict__ xb, float* __restrict__ rowsum)
{
  const long t = (long)blockIdx.x * 256 + threadIdx.x;
  const long i = t * 8;
  const f32x4 a = *(const f32x4*)(x + i);
  const f32x4 b = *(const f32x4*)(x + i + 4);
  union { bf16 h[8]; u32x4 u; } r;
#pragma unroll
  for (int q = 0; q < 4; ++q) { r.h[q] = (bf16)a[q]; r.h[4+q] = (bf16)b[q]; }
  *(u32x4*)(xb + i) = r.u;
  // per-row sum of bf16-rounded values (row = 4096 elems; wave covers 512, uniform row)
  float p = 0.f;
#pragma unroll
  for (int q = 0; q < 8; ++q) p += (float)r.h[q];
#pragma unroll
  for (int off = 32; off > 0; off >>= 1) p += __shfl_down(p, off);
  if ((threadIdx.x & 63) == 0) atomicAdd(&rowsum[(long)(t >> 9)], p);
}

// ---------- Pass 2: repack int32 -> bytes ----------
__global__ __launch_bounds__(256) void repack_w_kernel(
    const int* __restrict__ wp, unsigned int* __restrict__ wb)
{
  const long t = (long)blockIdx.x * 256 + threadIdx.x;   // 524,288 threads
  const long e = t * 16;
  u32x4 r;
#pragma unroll
  for (int q = 0; q < 4; ++q) {
    const int4 p = *(const int4*)(wp + e + q * 4);
    r[q] = (unsigned)(p.x & 255) | ((unsigned)(p.y & 255) << 8) |
           ((unsigned)(p.z & 255) << 16) | ((unsigned)(p.w & 255) << 24);
  }
  *(u32x4*)(wb + t * 4) = r;
}

// ---------- Pass 3: 256x256 fused-dequant GEMM ----------
// LDS: smA[2][2][256][32] bf16 (64 KB, st_16x32 swizzled);
//      smB[2][2][1024] u32 (16 KB) packed nibbles, word W (per half):
//      f=W&3, q=(W>>2)&3, l15=(W>>4)&15, wcg=W>>8 -> col n=wcg*64+f*16+l15,
//      K-half bytes q*4..q*4+3. Lane reads ONE b128 at ((wc*16+l15)*4+q)*16.
__global__ __launch_bounds__(512, 2) void gemm_bt_bias_kernel(
    const bf16* __restrict__ A, const unsigned char* __restrict__ WP,
    const float* __restrict__ scale, const float* __restrict__ zp,
    const float* __restrict__ bias, const float* __restrict__ rowsum,
    float* __restrict__ C)
{
  const int N = OUT_DIM, K = IN_DIM;
  const int NT = IN_DIM / 64;            // 64 K-tiles

  __shared__ bf16 smA[2][2][256][32];    // 64 KiB
  __shared__ unsigned int smB[2][2][1024]; // 16 KiB

  // T1: XCD-aware bijective swizzle (512 blocks)
  const int bid = blockIdx.x;
  const int swz = (bid & 7) * (512 / 8) + (bid >> 3);
  const int bm = swz >> 4;
  const int bn = swz & 15;

  const int tid  = threadIdx.x;
  const int lane = tid & 63;
  const int wave = tid >> 6;
  const int wr = wave >> 2;
  const int wc = wave & 3;

  const long row0 = (long)bm * 256;
  const long col0 = (long)bn * 256;

  // --- A staging source (pre-swizzled: linear LDS dest, swizzled global src) ---
  const int L0 = tid * 16;
  const int L1 = 8192 + tid * 16;
  const int Lw0 = L0 ^ (((L0 >> 9) & 1) << 5);
  const int Lw1 = L1 ^ (((L1 >> 9) & 1) << 5);
  const int sr0 = Lw0 >> 6, sc0 = (Lw0 & 63) >> 1;
  const int sr1 = Lw1 >> 6, sc1 = (Lw1 & 63) >> 1;
  const bf16* a0 = A + (row0 + sr0) * (long)K + sc0;
  const bf16* a1 = A + (row0 + sr1) * (long)K + sc1;

  // --- B staging sources (word W0=tid, W1=512+tid of the permuted half) ---
  const int W0 = tid, W1 = 512 + tid;
  const long bn0 = col0 + (W0 >> 8) * 64 + (W0 & 3) * 16 + ((W0 >> 4) & 15);
  const long bn1 = col0 + (W1 >> 8) * 64 + (W1 & 3) * 16 + ((W1 >> 4) & 15);
  const unsigned char* w0 = WP + bn0 * 2048L + ((W0 >> 2) & 3) * 4;
  const unsigned char* w1 = WP + bn1 * 2048L + ((W1 >> 2) & 3) * 4;

#define STAGE_G(BUF, KS, KOFF) do {                                             \
    char* Ah = (char*)&smA[BUF][KS][0][0];                                      \
    char* Bh = (char*)&smB[BUF][KS][0];                                         \
    __builtin_amdgcn_global_load_lds(                                           \
        (const __attribute__((address_space(1))) void*)(a0 + (KOFF)),           \
        (__attribute__((address_space(3))) void*)(Ah + L0), 16, 0, 0);          \
    __builtin_amdgcn_global_load_lds(                                           \
        (const __attribute__((address_space(1))) void*)(a1 + (KOFF)),           \
        (__attribute__((address_space(3))) void*)(Ah + L1), 16, 0, 0);          \
    __builtin_amdgcn_global_load_lds(                                           \
        (const __attribute__((address_space(1))) void*)(w0 + ((KOFF) >> 1)),    \
        (__attribute__((address_space(3))) void*)(Bh + tid * 4), 4, 0, 0);      \
    __builtin_amdgcn_global_load_lds(                                           \
        (const __attribute__((address_space(1))) void*)(w1 + ((KOFF) >> 1)),    \
        (__attribute__((address_space(3))) void*)(Bh + 2048 + tid * 4), 4, 0, 0);\
  } while (0)

  // --- read-side per-lane constants ---
  const int lane15 = lane & 15;
  const int rb  = (lane15 * 64 + ((lane >> 4) << 4)) ^ ((lane & 8) << 2);  // A swizzled
  const int wrB = wr * 8192;
  const int rBb = ((wc * 16 + lane15) * 4 + (lane >> 4)) * 16;             // B b128 byte addr

  // per-lane epilogue constants for the 4 col-frags
  float sv16[4], ev[4];
#pragma unroll
  for (int f = 0; f < 4; ++f) {
    const int n = (int)col0 + wc * 64 + f * 16 + lane15;
    const float s = scale[n];
    sv16[f] = 16.f * s;
    ev[f]   = s * (16.f + zp[n]);
  }

  f32x4 acc[8][4] = {};

#define PHASE(BUF, KS, STAGE_STMT, VM_STMT) do {                                \
    VM_STMT;                                                                    \
    __builtin_amdgcn_s_barrier();                                               \
    asm volatile("" ::: "memory");  /* keep LDS reads below the barrier */      \
    const char* Ab = (const char*)&smA[BUF][KS][0][0];                          \
    const char* Bp = (const char*)&smB[BUF][KS][0];                             \
    const u32x4 pkv = *(const u32x4*)(Bp + rBb);                                \
    bf16x8 fa[8];                                                               \
    _Pragma("unroll")                                                           \
    for (int f = 0; f < 8; ++f) fa[f] = *(const bf16x8*)(Ab + wrB + f * 1024 + rb); \
    STAGE_STMT;                                                                 \
    bf16x8 fb[4];                                                               \
    _Pragma("unroll")                                                           \
    for (int f = 0; f < 4; ++f) {                                               \
      union { unsigned int u[4]; bf16x8 h; } bb;                                \
      const unsigned int pk = pkv[f];                                           \
      _Pragma("unroll")                                                         \
      for (int g = 0; g < 4; ++g) {                                             \
        const unsigned int tt = pk >> (8 * g);                                  \
        bb.u[g] = 0x3F803F80u | ((tt & 15u) << 3) | ((tt & 0xF0u) << 15);       \
      }                                                                         \
      fb[f] = bb.h;                                                             \
    }                                                                           \
    __builtin_amdgcn_s_setprio(1);                                              \
    _Pragma("unroll")                                                           \
    for (int i = 0; i < 8; ++i)                                                 \
      _Pragma("unroll")                                                         \
      for (int j = 0; j < 4; ++j)                                               \
        acc[i][j] = __builtin_amdgcn_mfma_f32_16x16x32_bf16(fa[i], fb[j], acc[i][j], 0, 0, 0); \
    __builtin_amdgcn_s_setprio(0);                                              \
  } while (0)

  // Prologue: tile 0, both ks groups (8 ops in flight)
  STAGE_G(0, 0, 0);
  STAGE_G(0, 1, 32);

  for (int T = 0; T < NT; ++T) {
    const int buf = T & 1;
    const int nbuf = buf ^ 1;
    const int nko = (T + 1) * 64;
    const bool st = (T + 1 < NT);

    PHASE(buf, 0,
          { if (st) STAGE_G(nbuf, 0, nko); },
          { asm volatile("s_waitcnt vmcnt(4)" ::: "memory"); });
    PHASE(buf, 1,
          { if (st) STAGE_G(nbuf, 1, nko + 32); },
          { if (T == NT - 1) asm volatile("s_waitcnt vmcnt(0)" ::: "memory");
            else             asm volatile("s_waitcnt vmcnt(4)" ::: "memory"); });
  }

  // Epilogue: out = 16*s*acc - s*(16+zp)*rowsum + bias
  const long cr0 = row0 + wr * 128 + ((lane >> 4) << 2);
  const long cc0 = col0 + wc * 64 + lane15;
#pragma unroll
  for (int j = 0; j < 4; ++j) {
    const long gc = cc0 + j * 16;
    const float bv = bias[gc];
    const float sj = sv16[j], e = ev[j];
#pragma unroll
    for (int mf = 0; mf < 8; ++mf) {
      const long gr = cr0 + mf * 16;
      float* cp = C + gr * (long)N + gc;
#pragma unroll
      for (int r = 0; r < 4; ++r)
        cp[(long)r * N] = acc[mf][j][r] * sj - e * rowsum[gr + r] + bv;
    }
  }
#undef PHASE
#undef STAGE_G
}

extern "C" void kernel_launch(void* const* d_in, const int* in_sizes, int n_in,
                              void* d_out, int out_size, void* d_ws, size_t ws_size,
                              hipStream_t stream)
{
  const float* x     = (const float*)d_in[0];
  const int*   wp    = (const int*)d_in[1];     // int32 per packed byte
  const float* scale = (const float*)d_in[2];
  const float* zp    = (const float*)d_in[3];
  const float* bias  = (const float*)d_in[4];
  float* out = (float*)d_out;

  bf16* Xb = (bf16*)d_ws;                                         // 67,108,864 B
  unsigned int* Wb = (unsigned int*)((char*)d_ws + 67108864);     //  8,388,608 B
  float* Rs = (float*)((char*)d_ws + 67108864 + 8388608);         //     32,768 B

  hipMemsetAsync(Rs, 0, M_DIM * sizeof(float), stream);
  cvt_x_kernel<<<(M_DIM * (long)IN_DIM / 8) / 256, 256, 0, stream>>>(x, Xb, Rs);
  repack_w_kernel<<<(OUT_DIM * (long)IN_DIM / 2 / 16) / 256, 256, 0, stream>>>(wp, Wb);
  gemm_bt_bias_kernel<<<512, 512, 0, stream>>>(
      Xb, (const unsigned char*)Wb, scale, zp, bias, Rs, out);
}